// Round 1
// baseline (1082.316 us; speedup 1.0000x reference)
//
#include <hip/hip_runtime.h>
#include <stdint.h>
#include <math.h>

#define NB 16384  // batch

struct Ctrl {
  unsigned rank[4];
  unsigned key[4];
  float scale;
  unsigned pad[7];
};
static_assert(sizeof(Ctrl) == 64, "ctrl size");

__device__ __forceinline__ unsigned keyOf(float x) {
  unsigned u = __float_as_uint(x);
  return (u & 0x80000000u) ? ~u : (u | 0x80000000u);
}
__device__ __forceinline__ float keyToFloat(unsigned k) {
  unsigned u = (k & 0x80000000u) ? (k ^ 0x80000000u) : ~k;
  return __uint_as_float(u);
}

// ---------------- conv1 (1->6, 5x5, pad2) + relu + maxpool2 ----------------
// one block per image; x[b][0][28][28] -> out[b][6][14][14]
__global__ __launch_bounds__(256) void conv1_pool(
    const float* __restrict__ x, const float* __restrict__ w,
    const float* __restrict__ bias, float* __restrict__ out) {
  __shared__ float img[784];
  __shared__ float wl[150];
  __shared__ float bl[6];
  int t = threadIdx.x;
  int b = blockIdx.x;
  const float* xb = x + (size_t)b * 784;
  for (int i = t; i < 784; i += 256) img[i] = xb[i];
  if (t < 150) wl[t] = w[t];
  if (t < 6) bl[t] = bias[t];
  __syncthreads();
  for (int o = t; o < 1176; o += 256) {
    int c = o / 196;
    int rem = o % 196;
    int r = rem / 14, col = rem % 14;
    float win[6][6];
    int r0 = 2 * r - 2, c0 = 2 * col - 2;
#pragma unroll
    for (int i = 0; i < 6; i++) {
      int rr = r0 + i;
#pragma unroll
      for (int j = 0; j < 6; j++) {
        int cc = c0 + j;
        win[i][j] = (rr >= 0 && rr < 28 && cc >= 0 && cc < 28) ? img[rr * 28 + cc] : 0.0f;
      }
    }
    float s00 = 0.f, s01 = 0.f, s10 = 0.f, s11 = 0.f;
    const float* wc = &wl[c * 25];
#pragma unroll
    for (int i = 0; i < 5; i++) {
#pragma unroll
      for (int j = 0; j < 5; j++) {
        float wv = wc[i * 5 + j];
        s00 = fmaf(win[i][j], wv, s00);
        s01 = fmaf(win[i][j + 1], wv, s01);
        s10 = fmaf(win[i + 1][j], wv, s10);
        s11 = fmaf(win[i + 1][j + 1], wv, s11);
      }
    }
    float m = fmaxf(fmaxf(s00, s01), fmaxf(s10, s11));
    out[(size_t)b * 1176 + o] = fmaxf(m + bl[c], 0.0f);
  }
}

// ---------------- conv2 (6->16, 5x5, VALID) + relu + maxpool2 ----------------
// in[b][6][14][14] -> out[b][16][5][5]
__global__ __launch_bounds__(256) void conv2_pool(
    const float* __restrict__ a, const float* __restrict__ w,
    const float* __restrict__ bias, float* __restrict__ out) {
  __shared__ float img[1176];
  __shared__ float wl[2400];
  __shared__ float bl[16];
  int t = threadIdx.x;
  int b = blockIdx.x;
  const float* ab = a + (size_t)b * 1176;
  for (int i = t; i < 1176; i += 256) img[i] = ab[i];
  for (int i = t; i < 2400; i += 256) wl[i] = w[i];
  if (t < 16) bl[t] = bias[t];
  __syncthreads();
  for (int o = t; o < 400; o += 256) {
    int c = o / 25;
    int rem = o % 25;
    int r = rem / 5, col = rem % 5;
    float s00 = 0.f, s01 = 0.f, s10 = 0.f, s11 = 0.f;
    for (int ci = 0; ci < 6; ci++) {
      float win[6][6];
      const float* ic = &img[ci * 196 + (2 * r) * 14 + 2 * col];
#pragma unroll
      for (int i = 0; i < 6; i++)
#pragma unroll
        for (int j = 0; j < 6; j++) win[i][j] = ic[i * 14 + j];
      const float* wc = &wl[(c * 6 + ci) * 25];
#pragma unroll
      for (int i = 0; i < 5; i++) {
#pragma unroll
        for (int j = 0; j < 5; j++) {
          float wv = wc[i * 5 + j];
          s00 = fmaf(win[i][j], wv, s00);
          s01 = fmaf(win[i][j + 1], wv, s01);
          s10 = fmaf(win[i + 1][j], wv, s10);
          s11 = fmaf(win[i + 1][j + 1], wv, s11);
        }
      }
    }
    float m = fmaxf(fmaxf(s00, s01), fmaxf(s10, s11));
    out[(size_t)b * 400 + o] = fmaxf(m + bl[c], 0.0f);
  }
}

// ---------------- radix-select histograms ----------------
__global__ __launch_bounds__(256) void hist_top(
    const float4* __restrict__ a, long long n4, unsigned* __restrict__ hist) {
  __shared__ unsigned h[4096];
  int t = threadIdx.x;
  for (int i = t; i < 4096; i += 256) h[i] = 0;
  __syncthreads();
  long long stride = (long long)gridDim.x * 256;
  for (long long i = (long long)blockIdx.x * 256 + t; i < n4; i += stride) {
    float4 v = a[i];
    atomicAdd(&h[keyOf(v.x) >> 20], 1u);
    atomicAdd(&h[keyOf(v.y) >> 20], 1u);
    atomicAdd(&h[keyOf(v.z) >> 20], 1u);
    atomicAdd(&h[keyOf(v.w) >> 20], 1u);
  }
  __syncthreads();
  for (int i = t; i < 4096; i += 256) {
    unsigned v = h[i];
    if (v) atomicAdd(&hist[i], v);
  }
}

__global__ __launch_bounds__(256) void hist_sub(
    const float4* __restrict__ a, long long n4, const Ctrl* __restrict__ c,
    unsigned* __restrict__ hist, int level) {
  __shared__ unsigned h[4096];
  int t = threadIdx.x;
  for (int i = t; i < 4096; i += 256) h[i] = 0;
  __syncthreads();
  unsigned p0 = c->key[0], p1 = c->key[1], p2 = c->key[2], p3 = c->key[3];
  unsigned mask = (level == 2) ? 0xFFF00000u : 0xFFFFFC00u;
  int sh = (level == 2) ? 10 : 0;
  long long stride = (long long)gridDim.x * 256;
  for (long long i = (long long)blockIdx.x * 256 + t; i < n4; i += stride) {
    float4 v = a[i];
    float vals[4] = {v.x, v.y, v.z, v.w};
#pragma unroll
    for (int q = 0; q < 4; q++) {
      unsigned k = keyOf(vals[q]);
      unsigned pf = k & mask;
      unsigned bin = (k >> sh) & 1023u;
      if (pf == p0) atomicAdd(&h[bin], 1u);
      if (pf == p1) atomicAdd(&h[1024 + bin], 1u);
      if (pf == p2) atomicAdd(&h[2048 + bin], 1u);
      if (pf == p3) atomicAdd(&h[3072 + bin], 1u);
    }
  }
  __syncthreads();
  for (int i = t; i < 4096; i += 256) {
    unsigned v = h[i];
    if (v) atomicAdd(&hist[i], v);
  }
}

// one block; walks histogram level, refines rank/key for each of 4 targets
__global__ __launch_bounds__(256) void scan_step(
    const unsigned* __restrict__ hist, int nbins, int sharedHist, int shift,
    Ctrl* __restrict__ c, int first, unsigned r0, unsigned r1, unsigned r2,
    unsigned r3, int finalize, float lwlo, float hwlo, float lwhi, float hwhi) {
  __shared__ unsigned base[256];
  int t = threadIdx.x;
  unsigned rinit[4] = {r0, r1, r2, r3};
  int per = nbins / 256;
  for (int j = 0; j < 4; j++) {
    const unsigned* h = hist + (sharedHist ? 0 : j * nbins);
    unsigned s = 0;
    for (int i = 0; i < per; i++) s += h[t * per + i];
    base[t] = s;
    __syncthreads();
    if (t == 0) {
      unsigned acc = 0;
      for (int i = 0; i < 256; i++) {
        unsigned v = base[i];
        base[i] = acc;
        acc += v;
      }
    }
    __syncthreads();
    unsigned rank = first ? rinit[j] : c->rank[j];
    unsigned bexc = base[t];
    if (rank >= bexc && rank < bexc + s) {
      unsigned cum = bexc;
      for (int i = 0; i < per; i++) {
        unsigned cnt = h[t * per + i];
        if (rank < cum + cnt) {
          c->rank[j] = rank - cum;
          c->key[j] |= ((unsigned)(t * per + i)) << shift;
          break;
        }
        cum += cnt;
      }
    }
    __syncthreads();
  }
  if (finalize && t == 0) {
    float v0 = keyToFloat(c->key[0]), v1 = keyToFloat(c->key[1]);
    float v2 = keyToFloat(c->key[2]), v3 = keyToFloat(c->key[3]);
    // match lax: add(mul(lo,lw), mul(hi,hw)) with separate roundings (no fma)
    float plo = __fadd_rn(__fmul_rn(v0, lwlo), __fmul_rn(v1, hwlo));
    float phi = __fadd_rn(__fmul_rn(v2, lwhi), __fmul_rn(v3, hwhi));
    float am = fmaxf(fabsf(plo), fabsf(phi));
    c->scale = (am > 0.0f) ? __fdiv_rn(127.0f, am) : 128.0f;
  }
}

// ---------------- quantize map (in place) ----------------
__device__ __forceinline__ float qmap1(float x, float scale) {
  float t = __fmul_rn(x, scale);
  t = floorf(t);
  t = fminf(fmaxf(t, -128.0f), 127.0f);
  int qi = (int)t;
  int u2 = (qi & 0xF0) | 9;  // (q mod 256)&0xF0 | 0b1001
  int s = (u2 >= 128) ? (u2 - 256) : u2;
  return __fdiv_rn((float)s, scale);
}

__global__ __launch_bounds__(256) void quant_map(
    float4* __restrict__ a, long long n4, const Ctrl* __restrict__ c) {
  float scale = c->scale;
  long long stride = (long long)gridDim.x * 256;
  for (long long i = (long long)blockIdx.x * 256 + threadIdx.x; i < n4; i += stride) {
    float4 v = a[i];
    v.x = qmap1(v.x, scale);
    v.y = qmap1(v.y, scale);
    v.z = qmap1(v.z, scale);
    v.w = qmap1(v.w, scale);
    a[i] = v;
  }
}

// ---------------- FC layers ----------------
// fc1: [B,400] x [120,400]^T, relu. block: 32 rows, K chunked by 100.
__global__ __launch_bounds__(256) void fc1_kernel(
    const float* __restrict__ A, const float* __restrict__ W,
    const float* __restrict__ bias, float* __restrict__ out) {
  __shared__ float As[32][100];
  __shared__ float Ws[120][100];
  int t = threadIdx.x;
  size_t b0 = (size_t)blockIdx.x * 32;
  int ng = t & 7, bs = t >> 3;
  float acc[15];
#pragma unroll
  for (int i = 0; i < 15; i++) acc[i] = 0.f;
  for (int kc = 0; kc < 4; kc++) {
    for (int idx = t; idx < 3200; idx += 256) {
      int row = idx / 100, k = idx % 100;
      As[row][k] = A[(b0 + row) * 400 + kc * 100 + k];
    }
    for (int idx = t; idx < 12000; idx += 256) {
      int n = idx / 100, k = idx % 100;
      Ws[n][k] = W[n * 400 + kc * 100 + k];
    }
    __syncthreads();
    for (int k = 0; k < 100; k++) {
      float av = As[bs][k];
#pragma unroll
      for (int i = 0; i < 15; i++) acc[i] = fmaf(av, Ws[ng + 8 * i][k], acc[i]);
    }
    __syncthreads();
  }
#pragma unroll
  for (int i = 0; i < 15; i++) {
    int n = ng + 8 * i;
    out[(b0 + bs) * 120 + n] = fmaxf(acc[i] + bias[n], 0.0f);
  }
}

// fc2: [B,120] x [84,120]^T, relu. block: 64 rows. As padded to kill 4-way conflicts.
__global__ __launch_bounds__(256) void fc2_kernel(
    const float* __restrict__ A, const float* __restrict__ W,
    const float* __restrict__ bias, float* __restrict__ out) {
  __shared__ float As[64][121];
  __shared__ float Ws[84][120];
  int t = threadIdx.x;
  size_t b0 = (size_t)blockIdx.x * 64;
  int ng = t & 3, bs = t >> 2;
  float acc[21];
#pragma unroll
  for (int i = 0; i < 21; i++) acc[i] = 0.f;
  for (int idx = t; idx < 7680; idx += 256) {
    int row = idx / 120, k = idx % 120;
    As[row][k] = A[(b0 + row) * 120 + k];
  }
  for (int idx = t; idx < 10080; idx += 256) {
    int n = idx / 120, k = idx % 120;
    Ws[n][k] = W[n * 120 + k];
  }
  __syncthreads();
  for (int k = 0; k < 120; k++) {
    float av = As[bs][k];
#pragma unroll
    for (int i = 0; i < 21; i++) acc[i] = fmaf(av, Ws[ng + 4 * i][k], acc[i]);
  }
#pragma unroll
  for (int i = 0; i < 21; i++) {
    int n = ng + 4 * i;
    out[(b0 + bs) * 84 + n] = fmaxf(acc[i] + bias[n], 0.0f);
  }
}

// fc3: [B,84] x [10,84]^T, no relu -> d_out
__global__ __launch_bounds__(256) void fc3_kernel(
    const float* __restrict__ A, const float* __restrict__ W,
    const float* __restrict__ bias, float* __restrict__ out) {
  __shared__ float As[64][84];
  __shared__ float Ws[10][84];
  __shared__ float bl[10];
  int t = threadIdx.x;
  size_t b0 = (size_t)blockIdx.x * 64;
  int ng = t & 3, bs = t >> 2;
  for (int idx = t; idx < 5376; idx += 256) {
    int row = idx / 84, k = idx % 84;
    As[row][k] = A[(b0 + row) * 84 + k];
  }
  for (int idx = t; idx < 840; idx += 256) Ws[idx / 84][idx % 84] = W[idx];
  if (t < 10) bl[t] = bias[t];
  __syncthreads();
  float acc[3] = {0.f, 0.f, 0.f};
  for (int k = 0; k < 84; k++) {
    float av = As[bs][k];
#pragma unroll
    for (int i = 0; i < 3; i++) {
      int n = ng + 4 * i;
      if (n < 10) acc[i] = fmaf(av, Ws[n][k], acc[i]);
    }
  }
#pragma unroll
  for (int i = 0; i < 3; i++) {
    int n = ng + 4 * i;
    if (n < 10) out[(b0 + bs) * 10 + n] = acc[i] + bl[n];
  }
}

// ---------------- host ----------------
// Replicates jax f32 quantile index arithmetic exactly (IEEE f32 on host).
static void qparams(long long n, unsigned r[4], float w[4]) {
  float nf = (float)n;
  float nm1 = nf - 1.0f;  // note: for n=19267584 this stays 19267584.0f (ties-to-even), as in jax
  float qlo = 2.5f / 100.0f, qhi = 97.5f / 100.0f;
  float ilo = qlo * nm1;
  float flo = floorf(ilo), clo = ceilf(ilo);
  float hwlo = ilo - flo, lwlo = 1.0f - hwlo;
  float ihi = qhi * nm1;
  float fhi = floorf(ihi), chi = ceilf(ihi);
  float hwhi = ihi - fhi, lwhi = 1.0f - hwhi;
  if (flo < 0) flo = 0;
  if (clo < 0) clo = 0;
  if (fhi < 0) fhi = 0;
  if (chi < 0) chi = 0;
  unsigned nmax = (unsigned)(n - 1);
  r[0] = (unsigned)flo; if (r[0] > nmax) r[0] = nmax;
  r[1] = (unsigned)clo; if (r[1] > nmax) r[1] = nmax;
  r[2] = (unsigned)fhi; if (r[2] > nmax) r[2] = nmax;
  r[3] = (unsigned)chi; if (r[3] > nmax) r[3] = nmax;
  w[0] = lwlo; w[1] = hwlo; w[2] = lwhi; w[3] = hwhi;
}

extern "C" void kernel_launch(void* const* d_in, const int* in_sizes, int n_in,
                              void* d_out, int out_size, void* d_ws, size_t ws_size,
                              hipStream_t stream) {
  const float* x   = (const float*)d_in[0];
  const float* c1w = (const float*)d_in[1];
  const float* c1b = (const float*)d_in[2];
  const float* c2w = (const float*)d_in[3];
  const float* c2b = (const float*)d_in[4];
  const float* f1w = (const float*)d_in[5];
  const float* f1b = (const float*)d_in[6];
  const float* f2w = (const float*)d_in[7];
  const float* f2b = (const float*)d_in[8];
  const float* f3w = (const float*)d_in[9];
  const float* f3b = (const float*)d_in[10];
  float* outp = (float*)d_out;

  char* ws = (char*)d_ws;
  size_t off = 0;
  auto alloc = [&](size_t bytes) {
    void* p = ws + off;
    off += (bytes + 255) & ~(size_t)255;
    return p;
  };
  float* act1 = (float*)alloc((size_t)NB * 1176 * 4);  // 77.07 MB
  float* act2 = (float*)alloc((size_t)NB * 400 * 4);   // 26.21 MB
  unsigned* hist1 = (unsigned*)alloc(4096 * 4);
  unsigned* hist2 = (unsigned*)alloc(4096 * 4);
  unsigned* hist3 = (unsigned*)alloc(4096 * 4);
  Ctrl* ctrl = (Ctrl*)alloc(sizeof(Ctrl));
  // reuse act1 region after conv2 consumed it
  float* fc1o = act1;                     // 7.86 MB
  float* fc2o = act1 + (size_t)NB * 120;  // 5.5 MB (fits well inside act1 region)

  const int HB = 2048;  // grid for streaming passes

  auto runQuant = [&](float* act, long long n) {
    unsigned r[4];
    float w[4];
    qparams(n, r, w);
    // zero hist1..hist3 + ctrl (contiguous, each 256B-aligned size)
    hipMemsetAsync(hist1, 0, 3 * 4096 * 4 + sizeof(Ctrl), stream);
    long long n4 = n / 4;
    hist_top<<<HB, 256, 0, stream>>>((const float4*)act, n4, hist1);
    scan_step<<<1, 256, 0, stream>>>(hist1, 4096, 1, 20, ctrl, 1,
                                     r[0], r[1], r[2], r[3], 0, 0.f, 0.f, 0.f, 0.f);
    hist_sub<<<HB, 256, 0, stream>>>((const float4*)act, n4, ctrl, hist2, 2);
    scan_step<<<1, 256, 0, stream>>>(hist2, 1024, 0, 10, ctrl, 0,
                                     0u, 0u, 0u, 0u, 0, 0.f, 0.f, 0.f, 0.f);
    hist_sub<<<HB, 256, 0, stream>>>((const float4*)act, n4, ctrl, hist3, 3);
    scan_step<<<1, 256, 0, stream>>>(hist3, 1024, 0, 0, ctrl, 0,
                                     0u, 0u, 0u, 0u, 1, w[0], w[1], w[2], w[3]);
    quant_map<<<HB, 256, 0, stream>>>((float4*)act, n4, ctrl);
  };

  conv1_pool<<<NB, 256, 0, stream>>>(x, c1w, c1b, act1);
  runQuant(act1, (long long)NB * 1176);
  conv2_pool<<<NB, 256, 0, stream>>>(act1, c2w, c2b, act2);
  runQuant(act2, (long long)NB * 400);
  fc1_kernel<<<NB / 32, 256, 0, stream>>>(act2, f1w, f1b, fc1o);
  runQuant(fc1o, (long long)NB * 120);
  fc2_kernel<<<NB / 64, 256, 0, stream>>>(fc1o, f2w, f2b, fc2o);
  runQuant(fc2o, (long long)NB * 84);
  fc3_kernel<<<NB / 64, 256, 0, stream>>>(fc2o, f3w, f3b, outp);
}